// Round 1
// baseline (16792.804 us; speedup 1.0000x reference)
//
#include <hip/hip_runtime.h>

#define NN   50000
#define NE   800000
#define INCH 8
#define CH   128
#define EA   6
#define NB   2000
#define NCLS 32
#define FUS  384

// ---------- small helpers ----------
static __device__ __forceinline__ void atomic_max_pos(float* addr, float v) {
  // valid for non-negative floats: IEEE bits compare like uints
  atomicMax((unsigned int*)addr, __float_as_uint(v));
}

// ---------- degree of dst nodes ----------
__global__ __launch_bounds__(256) void k_deg(const int* __restrict__ edge,
                                             int* __restrict__ deg) {
  int e = blockIdx.x * 256 + threadIdx.x;
  if (e < NE) atomicAdd(&deg[edge[NE + e]], 1);
}

// ---------- segment starts from sorted bbox_idx ----------
__global__ __launch_bounds__(256) void k_segstart(const int* __restrict__ bbox,
                                                  int* __restrict__ seg) {
  int i = blockIdx.x * 256 + threadIdx.x;
  if (i >= NN) return;
  int bc = bbox[i];
  int bp = (i == 0) ? -1 : bbox[i - 1];
  for (int j = bp + 1; j <= bc; ++j) seg[j] = i;
  if (i == NN - 1)
    for (int j = bc + 1; j <= NB; ++j) seg[j] = NN;
}

// ---------- node transform: P = X@(W1-W2)+b, Q = X@W2 ----------
// X: row stride ldx, K input channels. W rows [0,K)=W1, [K,2K)=W2.
__global__ __launch_bounds__(128) void k_node_pq(
    const float* __restrict__ X, int ldx, int K,
    const float* __restrict__ W, const float* __restrict__ bias,
    float* __restrict__ P, float* __restrict__ Q) {
  const int oc = threadIdx.x;          // 0..127
  const int n0 = blockIdx.x * 4;       // 4 nodes per block, NN%4==0
  float bv = bias[oc];
  float p0 = bv, p1 = bv, p2 = bv, p3 = bv;
  float q0 = 0.f, q1 = 0.f, q2 = 0.f, q3 = 0.f;
  const float* x0 = X + (size_t)n0 * ldx;
  for (int k = 0; k < K; ++k) {
    float w1 = W[(size_t)k * CH + oc];
    float w2 = W[(size_t)(K + k) * CH + oc];
    float a  = w1 - w2;
    float xa = x0[k];
    float xb = x0[ldx + k];
    float xc = x0[2 * (size_t)ldx + k];
    float xd = x0[3 * (size_t)ldx + k];
    p0 += xa * a;  q0 += xa * w2;
    p1 += xb * a;  q1 += xb * w2;
    p2 += xc * a;  q2 += xc * w2;
    p3 += xd * a;  q3 += xd * w2;
  }
  size_t o = (size_t)n0 * CH + oc;
  P[o] = p0;          Q[o] = q0;
  P[o + CH] = p1;     Q[o + CH] = q1;
  P[o + 2 * CH] = p2; Q[o + 2 * CH] = q2;
  P[o + 3 * CH] = p3; Q[o + 3 * CH] = q3;
}

// ---------- edge pass: out[dst] (max or add) relu(P[src]+Q[dst]+e@C) ----------
// 4 threads per edge, 32 channels each. out points at the conv's 128-slice
// inside the [N,384] feature buffer (row stride FUS).
template <int MODE>  // 0 = atomic max, 1 = atomic add
__global__ __launch_bounds__(256) void k_edge(
    const int* __restrict__ edge, const float* __restrict__ eattr,
    const float* __restrict__ P, const float* __restrict__ Q,
    const float* __restrict__ C, float* __restrict__ out) {
  const int gid = blockIdx.x * 256 + threadIdx.x;
  const int e   = gid >> 2;
  const int c0  = (gid & 3) * 32;
  const int s = edge[e];
  const int d = edge[NE + e];
  float ea[EA];
#pragma unroll
  for (int j = 0; j < EA; ++j) ea[j] = eattr[(size_t)e * EA + j];
  const float* Pp = P + (size_t)s * CH + c0;
  const float* Qp = Q + (size_t)d * CH + c0;
  float* orow = out + (size_t)d * FUS + c0;
#pragma unroll
  for (int i = 0; i < 8; ++i) {
    float4 p = *(const float4*)(Pp + i * 4);
    float4 q = *(const float4*)(Qp + i * 4);
    float v[4] = {p.x + q.x, p.y + q.y, p.z + q.z, p.w + q.w};
#pragma unroll
    for (int j = 0; j < EA; ++j) {
      float ej = ea[j];
      const float4 cw = *(const float4*)(C + (size_t)j * CH + c0 + i * 4);
      v[0] += ej * cw.x; v[1] += ej * cw.y; v[2] += ej * cw.z; v[3] += ej * cw.w;
    }
#pragma unroll
    for (int u = 0; u < 4; ++u) {
      float r = fmaxf(v[u], 0.f);
      if (r > 0.f) {                       // zero contributes nothing to max or sum
        if (MODE == 0) atomic_max_pos(orow + i * 4 + u, r);
        else           atomicAdd(orow + i * 4 + u, r);
      }
    }
  }
}

// ---------- finalize conv slice: residual add + mean for super stream ----------
__global__ __launch_bounds__(256) void k_finalize(
    float* __restrict__ feats, float* __restrict__ sfeats,
    const int* __restrict__ deg, int cur, int prev) {
  int i = blockIdx.x * 256 + threadIdx.x;  // < NN*CH
  int n = i >> 7, c = i & 127;
  size_t o = (size_t)n * FUS + (size_t)cur * CH + c;
  float inv = 1.f / fmaxf((float)deg[n], 1.f);
  float s = sfeats[o] * inv;
  if (prev >= 0) {
    size_t op = (size_t)n * FUS + (size_t)prev * CH + c;
    feats[o] += feats[op];
    s += sfeats[op];
  }
  sfeats[o] = s;
}

// ---------- fused fusion-GEMM + bbox pooling (bbox_idx sorted -> no atomics) ----
// per block: one bbox. pooled[b][0:1024]=max relu(feats@Wf+bf); [1024:1408]=max feats
// sb[b][0:384] = mean sfeats
__global__ __launch_bounds__(256) void k_pool(
    const float* __restrict__ feats, const float* __restrict__ sfeats,
    const int* __restrict__ seg, const float* __restrict__ Wf,
    const float* __restrict__ bf, float* __restrict__ pooled,
    float* __restrict__ sb) {
  const int b = blockIdx.x, t = threadIdx.x;
  const int n0 = seg[b], n1 = seg[b + 1];
  const float4 b4 = *(const float4*)(bf + t * 4);
  float4 mx  = {0.f, 0.f, 0.f, 0.f};
  float4 fmx = {0.f, 0.f, 0.f, 0.f};
  float4 ss  = {0.f, 0.f, 0.f, 0.f};
  for (int nb = n0; nb < n1; nb += 8) {
    const int cnt = min(8, n1 - nb);
    float acc[8][4];
#pragma unroll
    for (int u = 0; u < 8; ++u)
      acc[u][0] = acc[u][1] = acc[u][2] = acc[u][3] = 0.f;
    for (int k = 0; k < FUS; ++k) {
      const float4 w = *(const float4*)(Wf + (size_t)k * 1024 + t * 4);
#pragma unroll
      for (int u = 0; u < 8; ++u) {
        // unconditional load: stays inside workspace; masked at merge
        float x = feats[(size_t)(nb + u) * FUS + k];
        acc[u][0] += x * w.x; acc[u][1] += x * w.y;
        acc[u][2] += x * w.z; acc[u][3] += x * w.w;
      }
    }
#pragma unroll
    for (int u = 0; u < 8; ++u)
      if (u < cnt) {
        mx.x = fmaxf(mx.x, acc[u][0] + b4.x);
        mx.y = fmaxf(mx.y, acc[u][1] + b4.y);
        mx.z = fmaxf(mx.z, acc[u][2] + b4.z);
        mx.w = fmaxf(mx.w, acc[u][3] + b4.w);
      }
    if (t < 96) {
      for (int u = 0; u < cnt; ++u) {
        const float4 f4 = *(const float4*)(feats + (size_t)(nb + u) * FUS + t * 4);
        fmx.x = fmaxf(fmx.x, f4.x); fmx.y = fmaxf(fmx.y, f4.y);
        fmx.z = fmaxf(fmx.z, f4.z); fmx.w = fmaxf(fmx.w, f4.w);
        const float4 s4 = *(const float4*)(sfeats + (size_t)(nb + u) * FUS + t * 4);
        ss.x += s4.x; ss.y += s4.y; ss.z += s4.z; ss.w += s4.w;
      }
    }
  }
  *(float4*)(pooled + (size_t)b * 1408 + t * 4) = mx;
  if (t < 96) {
    *(float4*)(pooled + (size_t)b * 1408 + 1024 + t * 4) = fmx;
    float inv = 1.f / fmaxf((float)(n1 - n0), 1.f);
    float4 o = {ss.x * inv, ss.y * inv, ss.z * inv, ss.w * inv};
    *(float4*)(sb + (size_t)b * FUS + t * 4) = o;
  }
}

// ---------- fusion_super = relu(sb @ Wfs + bfs), 8 bbox rows per block ----------
__global__ __launch_bounds__(256) void k_fusion_super(
    const float* __restrict__ sb, const float* __restrict__ Wfs,
    const float* __restrict__ bfs, float* __restrict__ fs) {
  const int r0 = blockIdx.x * 8, t = threadIdx.x;
  float acc[8][4];
#pragma unroll
  for (int u = 0; u < 8; ++u)
    acc[u][0] = acc[u][1] = acc[u][2] = acc[u][3] = 0.f;
  for (int k = 0; k < FUS; ++k) {
    const float4 w = *(const float4*)(Wfs + (size_t)k * 1024 + t * 4);
#pragma unroll
    for (int u = 0; u < 8; ++u) {
      float x = sb[(size_t)(r0 + u) * FUS + k];
      acc[u][0] += x * w.x; acc[u][1] += x * w.y;
      acc[u][2] += x * w.z; acc[u][3] += x * w.w;
    }
  }
  const float4 b4 = *(const float4*)(bfs + t * 4);
#pragma unroll
  for (int u = 0; u < 8; ++u) {
    float4 o = {fmaxf(acc[u][0] + b4.x, 0.f), fmaxf(acc[u][1] + b4.y, 0.f),
                fmaxf(acc[u][2] + b4.z, 0.f), fmaxf(acc[u][3] + b4.w, 0.f)};
    *(float4*)(fs + (size_t)(r0 + u) * 1024 + t * 4) = o;
  }
}

// ---------- h1 = relu(concat(pooled, fs, sb) @ W1 + b1) ----------
__global__ __launch_bounds__(256) void k_mlp1(
    const float* __restrict__ pooled, const float* __restrict__ fs,
    const float* __restrict__ sb, const float* __restrict__ W1,
    const float* __restrict__ b1, float* __restrict__ h1) {
  const int r0 = blockIdx.x * 8, t = threadIdx.x;  // oc = 2t, 2t+1
  float a0[8], a1[8];
#pragma unroll
  for (int u = 0; u < 8; ++u) { a0[u] = 0.f; a1[u] = 0.f; }
  for (int k = 0; k < 1408; ++k) {
    float2 w = *(const float2*)(W1 + (size_t)k * 512 + t * 2);
#pragma unroll
    for (int u = 0; u < 8; ++u) {
      float x = pooled[(size_t)(r0 + u) * 1408 + k];
      a0[u] += x * w.x; a1[u] += x * w.y;
    }
  }
  for (int k = 0; k < 1024; ++k) {
    float2 w = *(const float2*)(W1 + (size_t)(1408 + k) * 512 + t * 2);
#pragma unroll
    for (int u = 0; u < 8; ++u) {
      float x = fs[(size_t)(r0 + u) * 1024 + k];
      a0[u] += x * w.x; a1[u] += x * w.y;
    }
  }
  for (int k = 0; k < FUS; ++k) {
    float2 w = *(const float2*)(W1 + (size_t)(2432 + k) * 512 + t * 2);
#pragma unroll
    for (int u = 0; u < 8; ++u) {
      float x = sb[(size_t)(r0 + u) * FUS + k];
      a0[u] += x * w.x; a1[u] += x * w.y;
    }
  }
  float2 b = *(const float2*)(b1 + t * 2);
#pragma unroll
  for (int u = 0; u < 8; ++u) {
    h1[(size_t)(r0 + u) * 512 + t * 2]     = fmaxf(a0[u] + b.x, 0.f);
    h1[(size_t)(r0 + u) * 512 + t * 2 + 1] = fmaxf(a1[u] + b.y, 0.f);
  }
}

// ---------- h2 = relu(h1 @ W2 + b2) ----------
__global__ __launch_bounds__(256) void k_mlp2(
    const float* __restrict__ h1, const float* __restrict__ W2,
    const float* __restrict__ b2, float* __restrict__ h2) {
  const int r0 = blockIdx.x * 8, t = threadIdx.x;  // oc = t
  float acc[8];
#pragma unroll
  for (int u = 0; u < 8; ++u) acc[u] = 0.f;
  for (int k = 0; k < 512; ++k) {
    float w = W2[(size_t)k * 256 + t];
#pragma unroll
    for (int u = 0; u < 8; ++u) acc[u] += h1[(size_t)(r0 + u) * 512 + k] * w;
  }
  float bv = b2[t];
#pragma unroll
  for (int u = 0; u < 8; ++u)
    h2[(size_t)(r0 + u) * 256 + t] = fmaxf(acc[u] + bv, 0.f);
}

// ---------- logits = h2 @ W3 + b3 ----------
__global__ __launch_bounds__(256) void k_mlp3(
    const float* __restrict__ h2, const float* __restrict__ W3,
    const float* __restrict__ b3, float* __restrict__ out) {
  const int r0 = blockIdx.x * 8, t = threadIdx.x;
  const int u = t >> 5, oc = t & 31;
  const float* x = h2 + (size_t)(r0 + u) * 256;
  float acc = 0.f;
  for (int k = 0; k < 256; ++k) acc += x[k] * W3[(size_t)k * 32 + oc];
  out[(size_t)(r0 + u) * 32 + oc] = acc + b3[oc];
}

extern "C" void kernel_launch(void* const* d_in, const int* in_sizes, int n_in,
                              void* d_out, int out_size, void* d_ws, size_t ws_size,
                              hipStream_t stream) {
  const float* x     = (const float*)d_in[0];
  const float* eattr = (const float*)d_in[1];
  const float* W_h   = (const float*)d_in[2];
  const float* b_h   = (const float*)d_in[3];
  const float* Ws_h  = (const float*)d_in[4];
  const float* bs_h  = (const float*)d_in[5];
  const float* Wb    = (const float*)d_in[6];
  const float* bb    = (const float*)d_in[7];
  const float* Wbs   = (const float*)d_in[8];
  const float* bbs   = (const float*)d_in[9];
  const float* W_f   = (const float*)d_in[10];
  const float* b_f   = (const float*)d_in[11];
  const float* W_fs  = (const float*)d_in[12];
  const float* b_fs  = (const float*)d_in[13];
  const float* W1    = (const float*)d_in[14];
  const float* b1    = (const float*)d_in[15];
  const float* W2    = (const float*)d_in[16];
  const float* b2    = (const float*)d_in[17];
  const float* W3    = (const float*)d_in[18];
  const float* b3    = (const float*)d_in[19];
  const int*   edge  = (const int*)d_in[20];
  const int*   bbox  = (const int*)d_in[21];
  float* out = (float*)d_out;

  float* p = (float*)d_ws;
  float* feats  = p; p += (size_t)NN * FUS;   // [N,384] node stream (atomic max targets)
  float* sfeats = p; p += (size_t)NN * FUS;   // [N,384] super stream (atomic add targets)
  float* P      = p; p += (size_t)NN * CH;
  float* Q      = p; p += (size_t)NN * CH;
  float* sb     = p; p += (size_t)NB * FUS;
  float* fsup   = p; p += (size_t)NB * 1024;
  float* pooled = p; p += (size_t)NB * 1408;
  float* h1     = p; p += (size_t)NB * 512;
  float* h2     = p; p += (size_t)NB * 256;
  int* deg = (int*)p;
  int* seg = deg + NN;

  hipMemsetAsync(feats, 0, (size_t)2 * NN * FUS * sizeof(float), stream);
  hipMemsetAsync(deg, 0, NN * sizeof(int), stream);

  k_deg<<<(NE + 255) / 256, 256, 0, stream>>>(edge, deg);
  k_segstart<<<(NN + 255) / 256, 256, 0, stream>>>(bbox, seg);

  // conv 0 (head): both streams read x (K=8)
  k_node_pq<<<NN / 4, 128, 0, stream>>>(x, INCH, INCH, W_h, b_h, P, Q);
  k_edge<0><<<NE * 4 / 256, 256, 0, stream>>>(edge, eattr, P, Q, W_h + 2 * INCH * CH, feats);
  k_node_pq<<<NN / 4, 128, 0, stream>>>(x, INCH, INCH, Ws_h, bs_h, P, Q);
  k_edge<1><<<NE * 4 / 256, 256, 0, stream>>>(edge, eattr, P, Q, Ws_h + 2 * INCH * CH, sfeats);
  k_finalize<<<NN * CH / 256, 256, 0, stream>>>(feats, sfeats, deg, 0, -1);

  // residual blocks (K=128)
  for (int i = 0; i < 2; ++i) {
    const float* Wi  = Wb  + (size_t)i * 262 * CH;
    const float* bi  = bb  + (size_t)i * CH;
    const float* Wsi = Wbs + (size_t)i * 262 * CH;
    const float* bsi = bbs + (size_t)i * CH;
    k_node_pq<<<NN / 4, 128, 0, stream>>>(feats + i * CH, FUS, CH, Wi, bi, P, Q);
    k_edge<0><<<NE * 4 / 256, 256, 0, stream>>>(edge, eattr, P, Q, Wi + 2 * CH * CH,
                                                feats + (i + 1) * CH);
    k_node_pq<<<NN / 4, 128, 0, stream>>>(sfeats + i * CH, FUS, CH, Wsi, bsi, P, Q);
    k_edge<1><<<NE * 4 / 256, 256, 0, stream>>>(edge, eattr, P, Q, Wsi + 2 * CH * CH,
                                                sfeats + (i + 1) * CH);
    k_finalize<<<NN * CH / 256, 256, 0, stream>>>(feats, sfeats, deg, i + 1, i);
  }

  k_pool<<<NB, 256, 0, stream>>>(feats, sfeats, seg, W_f, b_f, pooled, sb);
  k_fusion_super<<<NB / 8, 256, 0, stream>>>(sb, W_fs, b_fs, fsup);
  k_mlp1<<<NB / 8, 256, 0, stream>>>(pooled, fsup, sb, W1, b1, h1);
  k_mlp2<<<NB / 8, 256, 0, stream>>>(h1, W2, b2, h2);
  k_mlp3<<<NB / 8, 256, 0, stream>>>(h2, W3, b3, out);
}

// Round 3
// 3374.968 us; speedup vs baseline: 4.9757x; 4.9757x over previous
//
#include <hip/hip_runtime.h>

#define NN   50000
#define NE   800000
#define INCH 8
#define CH   128
#define EA   6
#define NB   2000
#define NCLS 32
#define FUS  384

// ---------- degree of dst nodes ----------
__global__ __launch_bounds__(256) void k_deg(const int* __restrict__ edge,
                                             int* __restrict__ deg) {
  int e = blockIdx.x * 256 + threadIdx.x;
  if (e < NE) atomicAdd(&deg[edge[NE + e]], 1);
}

// ---------- exclusive scan of deg -> row_ptr (single block, shfl scan) ----------
__global__ __launch_bounds__(1024) void k_scan(const int* __restrict__ deg,
                                               int* __restrict__ row_ptr) {
  __shared__ int wsum[16];
  __shared__ int s_carry;
  const int t = threadIdx.x, lane = t & 63, w = t >> 6;
  if (t == 0) s_carry = 0;
  __syncthreads();
  for (int base = 0; base < NN; base += 1024) {
    int i = base + t;
    int x = (i < NN) ? deg[i] : 0;
#pragma unroll
    for (int off = 1; off < 64; off <<= 1) {
      int y = __shfl_up(x, off, 64);
      if (lane >= off) x += y;
    }
    if (lane == 63) wsum[w] = x;
    __syncthreads();
    if (w == 0 && lane < 16) {
      int s = wsum[lane];
#pragma unroll
      for (int off = 1; off < 16; off <<= 1) {
        int y = __shfl_up(s, off, 64);
        if (lane >= off) s += y;
      }
      wsum[lane] = s;
    }
    __syncthreads();
    int incl = x + ((w == 0) ? 0 : wsum[w - 1]) + s_carry;
    if (i < NN) row_ptr[i + 1] = incl;
    __syncthreads();
    if (t == 1023) s_carry = incl;
    __syncthreads();
  }
  if (t == 0) row_ptr[0] = 0;
}

// ---------- fill CSR: edge ids grouped by dst (no payload copy) ----------
__global__ __launch_bounds__(256) void k_fill(
    const int* __restrict__ edge, const int* __restrict__ row_ptr,
    int* __restrict__ cursor, int* __restrict__ eid_arr) {
  int e = blockIdx.x * 256 + threadIdx.x;
  if (e >= NE) return;
  int d = edge[NE + e];
  int idx = row_ptr[d] + atomicAdd(&cursor[d], 1);
  eid_arr[idx] = e;
}

// ---------- segment starts from sorted bbox_idx ----------
__global__ __launch_bounds__(256) void k_segstart(const int* __restrict__ bbox,
                                                  int* __restrict__ seg) {
  int i = blockIdx.x * 256 + threadIdx.x;
  if (i >= NN) return;
  int bc = bbox[i];
  int bp = (i == 0) ? -1 : bbox[i - 1];
  for (int j = bp + 1; j <= bc; ++j) seg[j] = i;
  if (i == NN - 1)
    for (int j = bc + 1; j <= NB; ++j) seg[j] = NN;
}

// ---------- node transform: P = X@(W1-W2)+b, Q = X@W2 ----------
__global__ __launch_bounds__(128) void k_node_pq(
    const float* __restrict__ X, int ldx, int K,
    const float* __restrict__ W, const float* __restrict__ bias,
    float* __restrict__ P, float* __restrict__ Q) {
  const int oc = threadIdx.x;          // 0..127
  const int n0 = blockIdx.x * 4;       // 4 nodes per block, NN%4==0
  float bv = bias[oc];
  float p0 = bv, p1 = bv, p2 = bv, p3 = bv;
  float q0 = 0.f, q1 = 0.f, q2 = 0.f, q3 = 0.f;
  const float* x0 = X + (size_t)n0 * ldx;
  for (int k = 0; k < K; ++k) {
    float w1 = W[(size_t)k * CH + oc];
    float w2 = W[(size_t)(K + k) * CH + oc];
    float a  = w1 - w2;
    float xa = x0[k];
    float xb = x0[ldx + k];
    float xc = x0[2 * (size_t)ldx + k];
    float xd = x0[3 * (size_t)ldx + k];
    p0 += xa * a;  q0 += xa * w2;
    p1 += xb * a;  q1 += xb * w2;
    p2 += xc * a;  q2 += xc * w2;
    p3 += xd * a;  q3 += xd * w2;
  }
  size_t o = (size_t)n0 * CH + oc;
  P[o] = p0;          Q[o] = q0;
  P[o + CH] = p1;     Q[o + CH] = q1;
  P[o + 2 * CH] = p2; Q[o + 2 * CH] = q2;
  P[o + 3 * CH] = p3; Q[o + 3 * CH] = q3;
}

// ---------- CSR conv (one stream), fused residual, no atomics ----------
// 2 nodes per 256-block, 128 threads (=channels) per node.
// MODE 0: out[cur] = max_e relu(P[src]+Q[dst]+e@C)      (+out[prev])
// MODE 1: out[cur] = mean_e relu(P[src]+Q[dst]+e@C)     (+out[prev])
template <int MODE>
__global__ __launch_bounds__(256) void k_conv(
    const int* __restrict__ row_ptr, const int* __restrict__ eid_arr,
    const int* __restrict__ edge, const float* __restrict__ eattr,
    const float* __restrict__ P, const float* __restrict__ Q,
    const float* __restrict__ C, float* __restrict__ outf,
    int cur, int prev) {
  const int t = threadIdx.x;
  const int node = blockIdx.x * 2 + (t >> 7);
  const int c = t & 127;
  float cw[EA];
#pragma unroll
  for (int j = 0; j < EA; ++j) cw[j] = C[j * CH + c];
  const int i0 = row_ptr[node], i1 = row_ptr[node + 1];
  const float q = Q[(size_t)node * CH + c];
  float acc = 0.f;
  for (int i = i0; i < i1; ++i) {
    const int e = eid_arr[i];                 // broadcast across lanes
    const int s = edge[e];                    // src (broadcast)
    const float* ep = eattr + (size_t)e * EA; // broadcast row
    float v = P[(size_t)s * CH + c] + q;      // coalesced 512B gather per node
#pragma unroll
    for (int j = 0; j < EA; ++j) v += ep[j] * cw[j];
    if (MODE == 0) acc = fmaxf(acc, v);       // seeded 0 == relu-max, empty-safe
    else           acc += fmaxf(v, 0.f);
  }
  if (MODE == 1) acc /= fmaxf((float)(i1 - i0), 1.f);
  size_t o = (size_t)node * FUS + (size_t)cur * CH + c;
  if (prev >= 0) acc += outf[(size_t)node * FUS + (size_t)prev * CH + c];
  outf[o] = acc;
}

// ---------- fused fusion-GEMM + bbox pooling (bbox_idx sorted -> no atomics) ----
__global__ __launch_bounds__(256) void k_pool(
    const float* __restrict__ feats, const float* __restrict__ sfeats,
    const int* __restrict__ seg, const float* __restrict__ Wf,
    const float* __restrict__ bf, float* __restrict__ pooled,
    float* __restrict__ sb) {
  const int b = blockIdx.x, t = threadIdx.x;
  const int n0 = seg[b], n1 = seg[b + 1];
  const float4 b4 = *(const float4*)(bf + t * 4);
  float4 mx  = {0.f, 0.f, 0.f, 0.f};
  float4 fmx = {0.f, 0.f, 0.f, 0.f};
  float4 ss  = {0.f, 0.f, 0.f, 0.f};
  for (int nb = n0; nb < n1; nb += 8) {
    const int cnt = min(8, n1 - nb);
    float acc[8][4];
#pragma unroll
    for (int u = 0; u < 8; ++u)
      acc[u][0] = acc[u][1] = acc[u][2] = acc[u][3] = 0.f;
    for (int k = 0; k < FUS; ++k) {
      const float4 w = *(const float4*)(Wf + (size_t)k * 1024 + t * 4);
#pragma unroll
      for (int u = 0; u < 8; ++u) {
        float x = feats[(size_t)(nb + u) * FUS + k];  // overread masked at merge
        acc[u][0] += x * w.x; acc[u][1] += x * w.y;
        acc[u][2] += x * w.z; acc[u][3] += x * w.w;
      }
    }
#pragma unroll
    for (int u = 0; u < 8; ++u)
      if (u < cnt) {
        mx.x = fmaxf(mx.x, acc[u][0] + b4.x);
        mx.y = fmaxf(mx.y, acc[u][1] + b4.y);
        mx.z = fmaxf(mx.z, acc[u][2] + b4.z);
        mx.w = fmaxf(mx.w, acc[u][3] + b4.w);
      }
    if (t < 96) {
      for (int u = 0; u < cnt; ++u) {
        const float4 f4 = *(const float4*)(feats + (size_t)(nb + u) * FUS + t * 4);
        fmx.x = fmaxf(fmx.x, f4.x); fmx.y = fmaxf(fmx.y, f4.y);
        fmx.z = fmaxf(fmx.z, f4.z); fmx.w = fmaxf(fmx.w, f4.w);
        const float4 s4 = *(const float4*)(sfeats + (size_t)(nb + u) * FUS + t * 4);
        ss.x += s4.x; ss.y += s4.y; ss.z += s4.z; ss.w += s4.w;
      }
    }
  }
  *(float4*)(pooled + (size_t)b * 1408 + t * 4) = mx;
  if (t < 96) {
    *(float4*)(pooled + (size_t)b * 1408 + 1024 + t * 4) = fmx;
    float inv = 1.f / fmaxf((float)(n1 - n0), 1.f);
    float4 o = {ss.x * inv, ss.y * inv, ss.z * inv, ss.w * inv};
    *(float4*)(sb + (size_t)b * FUS + t * 4) = o;
  }
}

// ---------- fusion_super = relu(sb @ Wfs + bfs) ----------
__global__ __launch_bounds__(256) void k_fusion_super(
    const float* __restrict__ sb, const float* __restrict__ Wfs,
    const float* __restrict__ bfs, float* __restrict__ fs) {
  const int r0 = blockIdx.x * 8, t = threadIdx.x;
  float acc[8][4];
#pragma unroll
  for (int u = 0; u < 8; ++u)
    acc[u][0] = acc[u][1] = acc[u][2] = acc[u][3] = 0.f;
  for (int k = 0; k < FUS; ++k) {
    const float4 w = *(const float4*)(Wfs + (size_t)k * 1024 + t * 4);
#pragma unroll
    for (int u = 0; u < 8; ++u) {
      float x = sb[(size_t)(r0 + u) * FUS + k];
      acc[u][0] += x * w.x; acc[u][1] += x * w.y;
      acc[u][2] += x * w.z; acc[u][3] += x * w.w;
    }
  }
  const float4 b4 = *(const float4*)(bfs + t * 4);
#pragma unroll
  for (int u = 0; u < 8; ++u) {
    float4 o = {fmaxf(acc[u][0] + b4.x, 0.f), fmaxf(acc[u][1] + b4.y, 0.f),
                fmaxf(acc[u][2] + b4.z, 0.f), fmaxf(acc[u][3] + b4.w, 0.f)};
    *(float4*)(fs + (size_t)(r0 + u) * 1024 + t * 4) = o;
  }
}

// ---------- h1 = relu(concat(pooled, fs, sb) @ W1 + b1) ----------
__global__ __launch_bounds__(256) void k_mlp1(
    const float* __restrict__ pooled, const float* __restrict__ fs,
    const float* __restrict__ sb, const float* __restrict__ W1,
    const float* __restrict__ b1, float* __restrict__ h1) {
  const int r0 = blockIdx.x * 8, t = threadIdx.x;  // oc = 2t, 2t+1
  float a0[8], a1[8];
#pragma unroll
  for (int u = 0; u < 8; ++u) { a0[u] = 0.f; a1[u] = 0.f; }
  for (int k = 0; k < 1408; ++k) {
    float2 w = *(const float2*)(W1 + (size_t)k * 512 + t * 2);
#pragma unroll
    for (int u = 0; u < 8; ++u) {
      float x = pooled[(size_t)(r0 + u) * 1408 + k];
      a0[u] += x * w.x; a1[u] += x * w.y;
    }
  }
  for (int k = 0; k < 1024; ++k) {
    float2 w = *(const float2*)(W1 + (size_t)(1408 + k) * 512 + t * 2);
#pragma unroll
    for (int u = 0; u < 8; ++u) {
      float x = fs[(size_t)(r0 + u) * 1024 + k];
      a0[u] += x * w.x; a1[u] += x * w.y;
    }
  }
  for (int k = 0; k < FUS; ++k) {
    float2 w = *(const float2*)(W1 + (size_t)(2432 + k) * 512 + t * 2);
#pragma unroll
    for (int u = 0; u < 8; ++u) {
      float x = sb[(size_t)(r0 + u) * FUS + k];
      a0[u] += x * w.x; a1[u] += x * w.y;
    }
  }
  float2 b = *(const float2*)(b1 + t * 2);
#pragma unroll
  for (int u = 0; u < 8; ++u) {
    h1[(size_t)(r0 + u) * 512 + t * 2]     = fmaxf(a0[u] + b.x, 0.f);
    h1[(size_t)(r0 + u) * 512 + t * 2 + 1] = fmaxf(a1[u] + b.y, 0.f);
  }
}

// ---------- h2 = relu(h1 @ W2 + b2) ----------
__global__ __launch_bounds__(256) void k_mlp2(
    const float* __restrict__ h1, const float* __restrict__ W2,
    const float* __restrict__ b2, float* __restrict__ h2) {
  const int r0 = blockIdx.x * 8, t = threadIdx.x;  // oc = t
  float acc[8];
#pragma unroll
  for (int u = 0; u < 8; ++u) acc[u] = 0.f;
  for (int k = 0; k < 512; ++k) {
    float w = W2[(size_t)k * 256 + t];
#pragma unroll
    for (int u = 0; u < 8; ++u) acc[u] += h1[(size_t)(r0 + u) * 512 + k] * w;
  }
  float bv = b2[t];
#pragma unroll
  for (int u = 0; u < 8; ++u)
    h2[(size_t)(r0 + u) * 256 + t] = fmaxf(acc[u] + bv, 0.f);
}

// ---------- logits = h2 @ W3 + b3 ----------
__global__ __launch_bounds__(256) void k_mlp3(
    const float* __restrict__ h2, const float* __restrict__ W3,
    const float* __restrict__ b3, float* __restrict__ out) {
  const int r0 = blockIdx.x * 8, t = threadIdx.x;
  const int u = t >> 5, oc = t & 31;
  const float* x = h2 + (size_t)(r0 + u) * 256;
  float acc = 0.f;
  for (int k = 0; k < 256; ++k) acc += x[k] * W3[(size_t)k * 32 + oc];
  out[(size_t)(r0 + u) * 32 + oc] = acc + b3[oc];
}

extern "C" void kernel_launch(void* const* d_in, const int* in_sizes, int n_in,
                              void* d_out, int out_size, void* d_ws, size_t ws_size,
                              hipStream_t stream) {
  const float* x     = (const float*)d_in[0];
  const float* eattr = (const float*)d_in[1];
  const float* W_h   = (const float*)d_in[2];
  const float* b_h   = (const float*)d_in[3];
  const float* Ws_h  = (const float*)d_in[4];
  const float* bs_h  = (const float*)d_in[5];
  const float* Wb    = (const float*)d_in[6];
  const float* bb    = (const float*)d_in[7];
  const float* Wbs   = (const float*)d_in[8];
  const float* bbs   = (const float*)d_in[9];
  const float* W_f   = (const float*)d_in[10];
  const float* b_f   = (const float*)d_in[11];
  const float* W_fs  = (const float*)d_in[12];
  const float* b_fs  = (const float*)d_in[13];
  const float* W1    = (const float*)d_in[14];
  const float* b1    = (const float*)d_in[15];
  const float* W2    = (const float*)d_in[16];
  const float* b2    = (const float*)d_in[17];
  const float* W3    = (const float*)d_in[18];
  const float* b3    = (const float*)d_in[19];
  const int*   edge  = (const int*)d_in[20];
  const int*   bbox  = (const int*)d_in[21];
  float* out = (float*)d_out;

  // ---- workspace layout (~209 MB; known-good budget >= 233 MB) ----
  float* p = (float*)d_ws;
  float* feats  = p; p += (size_t)NN * FUS;   // [N,384] node stream
  float* sfeats = p; p += (size_t)NN * FUS;   // [N,384] super stream
  float* P      = p; p += (size_t)NN * CH;    // shared by both streams (2 passes)
  float* Q      = p; p += (size_t)NN * CH;
  // head-MLP buffers overlap P/Q (dead after last conv):
  float* sb     = P;                         // 0.768M
  float* fsup   = P + (size_t)NB * FUS;      // 2.048M
  float* h1     = fsup + (size_t)NB * 1024;  // 1.024M
  float* h2     = h1 + (size_t)NB * 512;     // 0.512M  (total 4.352M <= 6.4M)
  float* pooled = Q;                         // 2.816M <= 6.4M
  int* eid_arr = (int*)p;                    // NE
  int* row_ptr = eid_arr + NE;               // NN+1
  int* deg     = row_ptr + NN + 1;           // NN
  int* cursor  = deg + NN;                   // NN
  int* seg     = cursor + NN;                // NB+1

  hipMemsetAsync(deg, 0, 2 * NN * sizeof(int), stream);  // deg + cursor

  // ---- CSR build (edge ids grouped by dst) + bbox segments ----
  k_deg<<<(NE + 255) / 256, 256, 0, stream>>>(edge, deg);
  k_scan<<<1, 1024, 0, stream>>>(deg, row_ptr);
  k_fill<<<(NE + 255) / 256, 256, 0, stream>>>(edge, row_ptr, cursor, eid_arr);
  k_segstart<<<(NN + 255) / 256, 256, 0, stream>>>(bbox, seg);

  // ---- conv 0 (head): both streams read x (K=8) ----
  k_node_pq<<<NN / 4, 128, 0, stream>>>(x, INCH, INCH, W_h, b_h, P, Q);
  k_conv<0><<<NN / 2, 256, 0, stream>>>(row_ptr, eid_arr, edge, eattr, P, Q,
                                        W_h + 2 * INCH * CH, feats, 0, -1);
  k_node_pq<<<NN / 4, 128, 0, stream>>>(x, INCH, INCH, Ws_h, bs_h, P, Q);
  k_conv<1><<<NN / 2, 256, 0, stream>>>(row_ptr, eid_arr, edge, eattr, P, Q,
                                        Ws_h + 2 * INCH * CH, sfeats, 0, -1);

  // ---- residual blocks (K=128) ----
  for (int i = 0; i < 2; ++i) {
    const float* Wi  = Wb  + (size_t)i * 262 * CH;
    const float* bi  = bb  + (size_t)i * CH;
    const float* Wsi = Wbs + (size_t)i * 262 * CH;
    const float* bsi = bbs + (size_t)i * CH;
    k_node_pq<<<NN / 4, 128, 0, stream>>>(feats + i * CH, FUS, CH, Wi, bi, P, Q);
    k_conv<0><<<NN / 2, 256, 0, stream>>>(row_ptr, eid_arr, edge, eattr, P, Q,
                                          Wi + 2 * CH * CH, feats, i + 1, i);
    k_node_pq<<<NN / 4, 128, 0, stream>>>(sfeats + i * CH, FUS, CH, Wsi, bsi, P, Q);
    k_conv<1><<<NN / 2, 256, 0, stream>>>(row_ptr, eid_arr, edge, eattr, P, Q,
                                          Wsi + 2 * CH * CH, sfeats, i + 1, i);
  }

  // ---- pooling + MLP head (P/Q regions reused as scratch) ----
  k_pool<<<NB, 256, 0, stream>>>(feats, sfeats, seg, W_f, b_f, pooled, sb);
  k_fusion_super<<<NB / 8, 256, 0, stream>>>(sb, W_fs, b_fs, fsup);
  k_mlp1<<<NB / 8, 256, 0, stream>>>(pooled, fsup, sb, W1, b1, h1);
  k_mlp2<<<NB / 8, 256, 0, stream>>>(h1, W2, b2, h2);
  k_mlp3<<<NB / 8, 256, 0, stream>>>(h2, W3, b3, out);
}

// Round 4
// 3105.778 us; speedup vs baseline: 5.4070x; 1.0867x over previous
//
#include <hip/hip_runtime.h>

#define NN   50000
#define NE   800000
#define INCH 8
#define CH   128
#define EA   6
#define NB   2000
#define NCLS 32
#define FUS  384

// ---------- degree of dst nodes ----------
__global__ __launch_bounds__(256) void k_deg(const int* __restrict__ edge,
                                             int* __restrict__ deg) {
  int e = blockIdx.x * 256 + threadIdx.x;
  if (e < NE) atomicAdd(&deg[edge[NE + e]], 1);
}

// ---------- exclusive scan of deg -> row_ptr (single block, shfl scan) ----------
__global__ __launch_bounds__(1024) void k_scan(const int* __restrict__ deg,
                                               int* __restrict__ row_ptr) {
  __shared__ int wsum[16];
  __shared__ int s_carry;
  const int t = threadIdx.x, lane = t & 63, w = t >> 6;
  if (t == 0) s_carry = 0;
  __syncthreads();
  for (int base = 0; base < NN; base += 1024) {
    int i = base + t;
    int x = (i < NN) ? deg[i] : 0;
#pragma unroll
    for (int off = 1; off < 64; off <<= 1) {
      int y = __shfl_up(x, off, 64);
      if (lane >= off) x += y;
    }
    if (lane == 63) wsum[w] = x;
    __syncthreads();
    if (w == 0 && lane < 16) {
      int s = wsum[lane];
#pragma unroll
      for (int off = 1; off < 16; off <<= 1) {
        int y = __shfl_up(s, off, 64);
        if (lane >= off) s += y;
      }
      wsum[lane] = s;
    }
    __syncthreads();
    int incl = x + ((w == 0) ? 0 : wsum[w - 1]) + s_carry;
    if (i < NN) row_ptr[i + 1] = incl;
    __syncthreads();
    if (t == 1023) s_carry = incl;
    __syncthreads();
  }
  if (t == 0) row_ptr[0] = 0;
}

// ---------- fill CSR: edge ids grouped by dst ----------
__global__ __launch_bounds__(256) void k_fill(
    const int* __restrict__ edge, const int* __restrict__ row_ptr,
    int* __restrict__ cursor, int* __restrict__ eid_arr) {
  int e = blockIdx.x * 256 + threadIdx.x;
  if (e >= NE) return;
  int d = edge[NE + e];
  int idx = row_ptr[d] + atomicAdd(&cursor[d], 1);
  eid_arr[idx] = e;
}

// ---------- segment starts from sorted bbox_idx ----------
__global__ __launch_bounds__(256) void k_segstart(const int* __restrict__ bbox,
                                                  int* __restrict__ seg) {
  int i = blockIdx.x * 256 + threadIdx.x;
  if (i >= NN) return;
  int bc = bbox[i];
  int bp = (i == 0) ? -1 : bbox[i - 1];
  for (int j = bp + 1; j <= bc; ++j) seg[j] = i;
  if (i == NN - 1)
    for (int j = bc + 1; j <= NB; ++j) seg[j] = NN;
}

// ---------- node transform: P = X@(W1-W2)+b, Q = X@W2 ----------
// NODES nodes per 128-thread block; x loads are provably block-uniform -> s_load.
template <int NODES>
__global__ __launch_bounds__(128) void k_node_pq(
    const float* __restrict__ X, int ldx, int K,
    const float* __restrict__ W, const float* __restrict__ bias,
    float* __restrict__ P, float* __restrict__ Q) {
  const int oc = threadIdx.x;          // 0..127
  const int n0 = blockIdx.x * NODES;
  float bv = bias[oc];
  float pacc[NODES], qacc[NODES];
#pragma unroll
  for (int u = 0; u < NODES; ++u) { pacc[u] = bv; qacc[u] = 0.f; }
  const float* x0 = X + (size_t)n0 * ldx;
  for (int k = 0; k < K; ++k) {
    float w1 = W[(size_t)k * CH + oc];
    float w2 = W[(size_t)(K + k) * CH + oc];
    float a  = w1 - w2;
#pragma unroll
    for (int u = 0; u < NODES; ++u) {
      float xv = x0[(size_t)u * ldx + k];
      pacc[u] += xv * a;
      qacc[u] += xv * w2;
    }
  }
#pragma unroll
  for (int u = 0; u < NODES; ++u) {
    size_t o = (size_t)(n0 + u) * CH + oc;
    P[o] = pacc[u];
    Q[o] = qacc[u];
  }
}

// ---------- CSR conv: one node per WAVE, lane-batched edge meta + shfl ----------
// lane owns channels (2*lane, 2*lane+1). Chunks of 64 edges: coalesced eid load,
// gathered src/e_attr, then per-edge shfl broadcast + independent P float2-gather.
// MODE 0: out[cur] = max_e relu(P[src]+Q[dst]+e@C)   (+out[prev])
// MODE 1: out[cur] = mean_e relu(P[src]+Q[dst]+e@C)  (+out[prev])
template <int MODE>
__global__ __launch_bounds__(256) void k_conv(
    const int* __restrict__ row_ptr, const int* __restrict__ eid_arr,
    const int* __restrict__ edge, const float* __restrict__ eattr,
    const float* __restrict__ P, const float* __restrict__ Q,
    const float* __restrict__ C, float* __restrict__ outf,
    int cur, int prev) {
  const int t = threadIdx.x;
  const int lane = t & 63;
  const int node = blockIdx.x * 4 + (t >> 6);
  const int c = lane * 2;
  float2 cw[EA];
#pragma unroll
  for (int j = 0; j < EA; ++j) cw[j] = *(const float2*)(C + j * CH + c);
  int i0 = __builtin_amdgcn_readfirstlane(row_ptr[node]);
  int i1 = __builtin_amdgcn_readfirstlane(row_ptr[node + 1]);
  const float2 q = *(const float2*)(Q + (size_t)node * CH + c);
  float a0 = 0.f, a1 = 0.f;
  for (int base = i0; base < i1; base += 64) {
    const int cnt = min(64, i1 - base);
    int s_l = 0;
    float ea0 = 0.f, ea1 = 0.f, ea2 = 0.f, ea3 = 0.f, ea4 = 0.f, ea5 = 0.f;
    if (lane < cnt) {
      int e = eid_arr[base + lane];      // coalesced
      s_l = edge[e];                     // gather
      const float* ep = eattr + (size_t)e * EA;
      ea0 = ep[0]; ea1 = ep[1]; ea2 = ep[2];
      ea3 = ep[3]; ea4 = ep[4]; ea5 = ep[5];
    }
#define EDGE_BODY(J)                                                       \
    {                                                                      \
      int s = __shfl(s_l, (J), 64);                                        \
      float e0 = __shfl(ea0, (J), 64), e1 = __shfl(ea1, (J), 64);          \
      float e2 = __shfl(ea2, (J), 64), e3 = __shfl(ea3, (J), 64);          \
      float e4 = __shfl(ea4, (J), 64), e5 = __shfl(ea5, (J), 64);          \
      const float2 pv = *(const float2*)(P + (size_t)s * CH + c);          \
      float v0 = pv.x + q.x, v1 = pv.y + q.y;                              \
      v0 += e0 * cw[0].x; v1 += e0 * cw[0].y;                              \
      v0 += e1 * cw[1].x; v1 += e1 * cw[1].y;                              \
      v0 += e2 * cw[2].x; v1 += e2 * cw[2].y;                              \
      v0 += e3 * cw[3].x; v1 += e3 * cw[3].y;                              \
      v0 += e4 * cw[4].x; v1 += e4 * cw[4].y;                              \
      v0 += e5 * cw[5].x; v1 += e5 * cw[5].y;                              \
      if (MODE == 0) { a0 = fmaxf(a0, v0); a1 = fmaxf(a1, v1); }           \
      else           { a0 += fmaxf(v0, 0.f); a1 += fmaxf(v1, 0.f); }       \
    }
    int j = 0;
    for (; j + 4 <= cnt; j += 4) {
      EDGE_BODY(j) EDGE_BODY(j + 1) EDGE_BODY(j + 2) EDGE_BODY(j + 3)
    }
    for (; j < cnt; ++j) EDGE_BODY(j)
#undef EDGE_BODY
  }
  if (MODE == 1) {
    float inv = 1.f / fmaxf((float)(i1 - i0), 1.f);
    a0 *= inv; a1 *= inv;
  }
  size_t o = (size_t)node * FUS + (size_t)cur * CH + c;
  if (prev >= 0) {
    const float2 pr = *(const float2*)(outf + (size_t)node * FUS + (size_t)prev * CH + c);
    a0 += pr.x; a1 += pr.y;
  }
  float2 ov = {a0, a1};
  *(float2*)(outf + o) = ov;
}

// ---------- fused fusion-GEMM + bbox pooling, LDS-staged transposed tile ----------
__global__ __launch_bounds__(256) void k_pool(
    const float* __restrict__ feats, const float* __restrict__ sfeats,
    const int* __restrict__ seg, const float* __restrict__ Wf,
    const float* __restrict__ bf, float* __restrict__ pooled,
    float* __restrict__ sb) {
  __shared__ float xT[FUS * 8];        // [k][u], 12.3 KB
  const int b = blockIdx.x, t = threadIdx.x;
  const int n0 = __builtin_amdgcn_readfirstlane(seg[b]);
  const int n1 = __builtin_amdgcn_readfirstlane(seg[b + 1]);
  const float4 b4 = *(const float4*)(bf + t * 4);
  float4 mx  = {0.f, 0.f, 0.f, 0.f};
  float4 fmx = {0.f, 0.f, 0.f, 0.f};
  float4 ss  = {0.f, 0.f, 0.f, 0.f};
  for (int nb = n0; nb < n1; nb += 8) {
    const int cnt = min(8, n1 - nb);
    __syncthreads();                   // protect xT from previous chunk readers
#pragma unroll
    for (int r = 0; r < 12; ++r) {     // 3072 floats / 256 threads
      int flat = r * 256 + t;
      int u = flat / FUS;
      int k = flat - u * FUS;
      // overread past n1 stays inside workspace; masked at merge
      xT[k * 8 + u] = feats[(size_t)(nb + u) * FUS + k];
    }
    __syncthreads();
    float acc[8][4];
#pragma unroll
    for (int u = 0; u < 8; ++u)
      acc[u][0] = acc[u][1] = acc[u][2] = acc[u][3] = 0.f;
#pragma unroll 2
    for (int k = 0; k < FUS; ++k) {
      const float4 w = *(const float4*)(Wf + (size_t)k * 1024 + t * 4);
      const float2 xa = *(const float2*)(xT + k * 8);
      const float2 xb = *(const float2*)(xT + k * 8 + 2);
      const float2 xc = *(const float2*)(xT + k * 8 + 4);
      const float2 xd = *(const float2*)(xT + k * 8 + 6);
      const float xs[8] = {xa.x, xa.y, xb.x, xb.y, xc.x, xc.y, xd.x, xd.y};
#pragma unroll
      for (int u = 0; u < 8; ++u) {
        acc[u][0] += xs[u] * w.x; acc[u][1] += xs[u] * w.y;
        acc[u][2] += xs[u] * w.z; acc[u][3] += xs[u] * w.w;
      }
    }
#pragma unroll
    for (int u = 0; u < 8; ++u)
      if (u < cnt) {
        mx.x = fmaxf(mx.x, acc[u][0] + b4.x);
        mx.y = fmaxf(mx.y, acc[u][1] + b4.y);
        mx.z = fmaxf(mx.z, acc[u][2] + b4.z);
        mx.w = fmaxf(mx.w, acc[u][3] + b4.w);
      }
    if (t < 96) {
      for (int u = 0; u < cnt; ++u) {
        const float4 f4 = *(const float4*)(feats + (size_t)(nb + u) * FUS + t * 4);
        fmx.x = fmaxf(fmx.x, f4.x); fmx.y = fmaxf(fmx.y, f4.y);
        fmx.z = fmaxf(fmx.z, f4.z); fmx.w = fmaxf(fmx.w, f4.w);
        const float4 s4 = *(const float4*)(sfeats + (size_t)(nb + u) * FUS + t * 4);
        ss.x += s4.x; ss.y += s4.y; ss.z += s4.z; ss.w += s4.w;
      }
    }
  }
  *(float4*)(pooled + (size_t)b * 1408 + t * 4) = mx;
  if (t < 96) {
    *(float4*)(pooled + (size_t)b * 1408 + 1024 + t * 4) = fmx;
    float inv = 1.f / fmaxf((float)(n1 - n0), 1.f);
    float4 o = {ss.x * inv, ss.y * inv, ss.z * inv, ss.w * inv};
    *(float4*)(sb + (size_t)b * FUS + t * 4) = o;
  }
}

// ---------- fusion_super = relu(sb @ Wfs + bfs) ----------
__global__ __launch_bounds__(256) void k_fusion_super(
    const float* __restrict__ sb, const float* __restrict__ Wfs,
    const float* __restrict__ bfs, float* __restrict__ fs) {
  const int r0 = blockIdx.x * 8, t = threadIdx.x;
  float acc[8][4];
#pragma unroll
  for (int u = 0; u < 8; ++u)
    acc[u][0] = acc[u][1] = acc[u][2] = acc[u][3] = 0.f;
  for (int k = 0; k < FUS; ++k) {
    const float4 w = *(const float4*)(Wfs + (size_t)k * 1024 + t * 4);
#pragma unroll
    for (int u = 0; u < 8; ++u) {
      float x = sb[(size_t)(r0 + u) * FUS + k];
      acc[u][0] += x * w.x; acc[u][1] += x * w.y;
      acc[u][2] += x * w.z; acc[u][3] += x * w.w;
    }
  }
  const float4 b4 = *(const float4*)(bfs + t * 4);
#pragma unroll
  for (int u = 0; u < 8; ++u) {
    float4 o = {fmaxf(acc[u][0] + b4.x, 0.f), fmaxf(acc[u][1] + b4.y, 0.f),
                fmaxf(acc[u][2] + b4.z, 0.f), fmaxf(acc[u][3] + b4.w, 0.f)};
    *(float4*)(fs + (size_t)(r0 + u) * 1024 + t * 4) = o;
  }
}

// ---------- h1 = relu(concat(pooled, fs, sb) @ W1 + b1), column-split ----------
__global__ __launch_bounds__(256) void k_mlp1(
    const float* __restrict__ pooled, const float* __restrict__ fs,
    const float* __restrict__ sb, const float* __restrict__ W1,
    const float* __restrict__ b1, float* __restrict__ h1) {
  const int r0 = blockIdx.x * 8;
  const int col = blockIdx.y * 256 + threadIdx.x;
  float acc[8];
#pragma unroll
  for (int u = 0; u < 8; ++u) acc[u] = 0.f;
  for (int k = 0; k < 1408; ++k) {
    float w = W1[(size_t)k * 512 + col];
#pragma unroll
    for (int u = 0; u < 8; ++u) acc[u] += pooled[(size_t)(r0 + u) * 1408 + k] * w;
  }
  for (int k = 0; k < 1024; ++k) {
    float w = W1[(size_t)(1408 + k) * 512 + col];
#pragma unroll
    for (int u = 0; u < 8; ++u) acc[u] += fs[(size_t)(r0 + u) * 1024 + k] * w;
  }
  for (int k = 0; k < FUS; ++k) {
    float w = W1[(size_t)(2432 + k) * 512 + col];
#pragma unroll
    for (int u = 0; u < 8; ++u) acc[u] += sb[(size_t)(r0 + u) * FUS + k] * w;
  }
  float bv = b1[col];
#pragma unroll
  for (int u = 0; u < 8; ++u)
    h1[(size_t)(r0 + u) * 512 + col] = fmaxf(acc[u] + bv, 0.f);
}

// ---------- h2 = relu(h1 @ W2 + b2) ----------
__global__ __launch_bounds__(256) void k_mlp2(
    const float* __restrict__ h1, const float* __restrict__ W2,
    const float* __restrict__ b2, float* __restrict__ h2) {
  const int r0 = blockIdx.x * 8, t = threadIdx.x;
  float acc[8];
#pragma unroll
  for (int u = 0; u < 8; ++u) acc[u] = 0.f;
  for (int k = 0; k < 512; ++k) {
    float w = W2[(size_t)k * 256 + t];
#pragma unroll
    for (int u = 0; u < 8; ++u) acc[u] += h1[(size_t)(r0 + u) * 512 + k] * w;
  }
  float bv = b2[t];
#pragma unroll
  for (int u = 0; u < 8; ++u)
    h2[(size_t)(r0 + u) * 256 + t] = fmaxf(acc[u] + bv, 0.f);
}

// ---------- logits = h2 @ W3 + b3 ----------
__global__ __launch_bounds__(256) void k_mlp3(
    const float* __restrict__ h2, const float* __restrict__ W3,
    const float* __restrict__ b3, float* __restrict__ out) {
  const int r0 = blockIdx.x * 8, t = threadIdx.x;
  const int u = t >> 5, oc = t & 31;
  const float* x = h2 + (size_t)(r0 + u) * 256;
  float acc = 0.f;
  for (int k = 0; k < 256; ++k) acc += x[k] * W3[(size_t)k * 32 + oc];
  out[(size_t)(r0 + u) * 32 + oc] = acc + b3[oc];
}

extern "C" void kernel_launch(void* const* d_in, const int* in_sizes, int n_in,
                              void* d_out, int out_size, void* d_ws, size_t ws_size,
                              hipStream_t stream) {
  const float* x     = (const float*)d_in[0];
  const float* eattr = (const float*)d_in[1];
  const float* W_h   = (const float*)d_in[2];
  const float* b_h   = (const float*)d_in[3];
  const float* Ws_h  = (const float*)d_in[4];
  const float* bs_h  = (const float*)d_in[5];
  const float* Wb    = (const float*)d_in[6];
  const float* bb    = (const float*)d_in[7];
  const float* Wbs   = (const float*)d_in[8];
  const float* bbs   = (const float*)d_in[9];
  const float* W_f   = (const float*)d_in[10];
  const float* b_f   = (const float*)d_in[11];
  const float* W_fs  = (const float*)d_in[12];
  const float* b_fs  = (const float*)d_in[13];
  const float* W1    = (const float*)d_in[14];
  const float* b1    = (const float*)d_in[15];
  const float* W2    = (const float*)d_in[16];
  const float* b2    = (const float*)d_in[17];
  const float* W3    = (const float*)d_in[18];
  const float* b3    = (const float*)d_in[19];
  const int*   edge  = (const int*)d_in[20];
  const int*   bbox  = (const int*)d_in[21];
  float* out = (float*)d_out;

  // ---- workspace layout (~209 MB; known-good budget >= 233 MB) ----
  float* p = (float*)d_ws;
  float* feats  = p; p += (size_t)NN * FUS;
  float* sfeats = p; p += (size_t)NN * FUS;
  float* P      = p; p += (size_t)NN * CH;
  float* Q      = p; p += (size_t)NN * CH;
  float* sb     = P;                         // overlap: dead after convs
  float* fsup   = P + (size_t)NB * FUS;
  float* h1     = fsup + (size_t)NB * 1024;
  float* h2     = h1 + (size_t)NB * 512;
  float* pooled = Q;
  int* eid_arr = (int*)p;
  int* row_ptr = eid_arr + NE;
  int* deg     = row_ptr + NN + 1;
  int* cursor  = deg + NN;
  int* seg     = cursor + NN;

  hipMemsetAsync(deg, 0, 2 * NN * sizeof(int), stream);  // deg + cursor

  // ---- CSR build + bbox segments ----
  k_deg<<<(NE + 255) / 256, 256, 0, stream>>>(edge, deg);
  k_scan<<<1, 1024, 0, stream>>>(deg, row_ptr);
  k_fill<<<(NE + 255) / 256, 256, 0, stream>>>(edge, row_ptr, cursor, eid_arr);
  k_segstart<<<(NN + 255) / 256, 256, 0, stream>>>(bbox, seg);

  // ---- conv 0 (head): both streams read x (K=8) ----
  k_node_pq<4><<<NN / 4, 128, 0, stream>>>(x, INCH, INCH, W_h, b_h, P, Q);
  k_conv<0><<<NN / 4, 256, 0, stream>>>(row_ptr, eid_arr, edge, eattr, P, Q,
                                        W_h + 2 * INCH * CH, feats, 0, -1);
  k_node_pq<4><<<NN / 4, 128, 0, stream>>>(x, INCH, INCH, Ws_h, bs_h, P, Q);
  k_conv<1><<<NN / 4, 256, 0, stream>>>(row_ptr, eid_arr, edge, eattr, P, Q,
                                        Ws_h + 2 * INCH * CH, sfeats, 0, -1);

  // ---- residual blocks (K=128) ----
  for (int i = 0; i < 2; ++i) {
    const float* Wi  = Wb  + (size_t)i * 262 * CH;
    const float* bi  = bb  + (size_t)i * CH;
    const float* Wsi = Wbs + (size_t)i * 262 * CH;
    const float* bsi = bbs + (size_t)i * CH;
    k_node_pq<16><<<NN / 16, 128, 0, stream>>>(feats + i * CH, FUS, CH, Wi, bi, P, Q);
    k_conv<0><<<NN / 4, 256, 0, stream>>>(row_ptr, eid_arr, edge, eattr, P, Q,
                                          Wi + 2 * CH * CH, feats, i + 1, i);
    k_node_pq<16><<<NN / 16, 128, 0, stream>>>(sfeats + i * CH, FUS, CH, Wsi, bsi, P, Q);
    k_conv<1><<<NN / 4, 256, 0, stream>>>(row_ptr, eid_arr, edge, eattr, P, Q,
                                          Wsi + 2 * CH * CH, sfeats, i + 1, i);
  }

  // ---- pooling + MLP head ----
  k_pool<<<NB, 256, 0, stream>>>(feats, sfeats, seg, W_f, b_f, pooled, sb);
  k_fusion_super<<<NB / 8, 256, 0, stream>>>(sb, W_fs, b_fs, fsup);
  k_mlp1<<<dim3(NB / 8, 2), 256, 0, stream>>>(pooled, fsup, sb, W1, b1, h1);
  k_mlp2<<<NB / 8, 256, 0, stream>>>(h1, W2, b2, h2);
  k_mlp3<<<NB / 8, 256, 0, stream>>>(h2, W3, b3, out);
}